// Round 2
// baseline (319.721 us; speedup 1.0000x reference)
//
#include <hip/hip_runtime.h>

#define N_NODES 50000
#define N_EDGES 800000
#define IN_F 256
#define OUT_F 64
#define HEADS 4
#define HF 256  // HEADS*OUT_F
#define NEG_SLOPE 0.2f

typedef __bf16 bf16x8 __attribute__((ext_vector_type(8)));
typedef float f32x4 __attribute__((ext_vector_type(4)));

// ---- monotone float<->uint encoding for atomicMax on floats ----
__device__ __forceinline__ unsigned encf(float f) {
  unsigned u = __float_as_uint(f);
  return (u & 0x80000000u) ? ~u : (u | 0x80000000u);
}
__device__ __forceinline__ float decf(unsigned k) {
  unsigned u = (k & 0x80000000u) ? (k & 0x7FFFFFFFu) : ~k;
  return __uint_as_float(u);
}
// fp32 -> bf16 (round-to-nearest-even)
__device__ __forceinline__ unsigned short f2bf(float f) {
  unsigned u = __float_as_uint(f);
  u += 0x7FFFu + ((u >> 16) & 1u);
  return (unsigned short)(u >> 16);
}
__device__ __forceinline__ float bflo(unsigned u) { return __uint_as_float(u << 16); }
__device__ __forceinline__ float bfhi(unsigned u) { return __uint_as_float(u & 0xFFFF0000u); }

// ---- Pack W into MFMA B-fragment layout (bf16) ----
// wb[((hd*4+nt)*8 + kt)*512 + l*8 + j] = bf16(W[hd][kt*32+(l>>4)*8+j][nt*16+(l&15)])
__global__ __launch_bounds__(256) void k_pack_w(const float* __restrict__ W,
                                                unsigned short* __restrict__ wb) {
  int idx = blockIdx.x * 256 + threadIdx.x;  // 65536
  int j = idx & 7, l = (idx >> 3) & 63, kt = (idx >> 9) & 7;
  int w = (idx >> 12) & 3, hd = (idx >> 14) & 3;
  int k = kt * 32 + (l >> 4) * 8 + j;
  int o = w * 16 + (l & 15);
  wb[idx] = f2bf(W[((size_t)hd * IN_F + k) * OUT_F + o]);
}

// ---- Kernel 1: MFMA GEMM h = x@W (f32 in, bf16 MFMA, fp32 acc) ----
// Block = 64 rows x ALL 256 cols. Wave w owns head w (4 Mtiles x 4 Ntiles
// C-frags, 128 MFMAs). x read ONCE, converted to bf16 in-register.
// Epilogue (attn logits) is fully in-wave: no LDS, no __syncthreads.
__global__ __launch_bounds__(256) void k_gemm(const float* __restrict__ x,
                                              const unsigned short* __restrict__ wb,
                                              const float* __restrict__ a_src,
                                              const float* __restrict__ a_dst,
                                              unsigned short* __restrict__ hb,
                                              float* __restrict__ as_out,
                                              float* __restrict__ ad_out) {
  const int t = threadIdx.x;
  const int hd = t >> 6, l = t & 63;
  const int quad = l >> 4, col = l & 15;
  const int blk = blockIdx.x;
  f32x4 acc[4][4];
#pragma unroll
  for (int ms = 0; ms < 4; ms++)
#pragma unroll
    for (int nt = 0; nt < 4; nt++) acc[ms][nt] = (f32x4){0.f, 0.f, 0.f, 0.f};

  // A-frag source: lane l covers x[mt*16 + col][kt*32 + quad*8 .. +8]
  const float* ab[4];
#pragma unroll
  for (int ms = 0; ms < 4; ms++) {
    int mt = blk * 4 + ms;
    if (mt > 3124) mt = 3124;  // tail: compute duplicated, stores guarded by m<N
    ab[ms] = x + (size_t)(mt * 16 + col) * IN_F + quad * 8;
  }
  const unsigned short* wbase = wb + (size_t)hd * 16384 + l * 8;

  for (int kt = 0; kt < 8; kt++) {
    union { uint4 u; bf16x8 v; } b[4], a[4];
#pragma unroll
    for (int nt = 0; nt < 4; nt++)
      b[nt].u = *(const uint4*)(wbase + (nt * 8 + kt) * 512);
#pragma unroll
    for (int ms = 0; ms < 4; ms++) {
      float4 v0 = *(const float4*)(ab[ms] + kt * 32);
      float4 v1 = *(const float4*)(ab[ms] + kt * 32 + 4);
      uint4 o;
      o.x = (unsigned)f2bf(v0.x) | ((unsigned)f2bf(v0.y) << 16);
      o.y = (unsigned)f2bf(v0.z) | ((unsigned)f2bf(v0.w) << 16);
      o.z = (unsigned)f2bf(v1.x) | ((unsigned)f2bf(v1.y) << 16);
      o.w = (unsigned)f2bf(v1.z) | ((unsigned)f2bf(v1.w) << 16);
      a[ms].u = o;
    }
#pragma unroll
    for (int ms = 0; ms < 4; ms++)
#pragma unroll
      for (int nt = 0; nt < 4; nt++)
        acc[ms][nt] = __builtin_amdgcn_mfma_f32_16x16x32_bf16(a[ms].v, b[nt].v, acc[ms][nt], 0, 0, 0);
  }

  // C/D layout: col = lane&15, row = quad*4 + r  [verified m89/m91]
  float avs[4], avd[4];
#pragma unroll
  for (int nt = 0; nt < 4; nt++) {
    avs[nt] = a_src[hd * OUT_F + nt * 16 + col];
    avd[nt] = a_dst[hd * OUT_F + nt * 16 + col];
  }
#pragma unroll
  for (int ms = 0; ms < 4; ms++) {
    int mbase = blk * 64 + ms * 16 + quad * 4;
#pragma unroll
    for (int r = 0; r < 4; r++) {
      int m = mbase + r;
      float ps = 0.f, pd = 0.f;
#pragma unroll
      for (int nt = 0; nt < 4; nt++) {
        float hv = acc[ms][nt][r];
        if (m < N_NODES)
          hb[(size_t)m * HF + hd * OUT_F + nt * 16 + col] = f2bf(hv);
        ps += hv * avs[nt];
        pd += hv * avd[nt];
      }
#pragma unroll
      for (int off = 8; off > 0; off >>= 1) {
        ps += __shfl_down(ps, off, 16);
        pd += __shfl_down(pd, off, 16);
      }
      if (col == 0 && m < N_NODES) {
        as_out[hd * N_NODES + m] = ps;
        ad_out[hd * N_NODES + m] = pd;
      }
    }
  }
}

// ---- Kernel 2: global max of e over [H,E] + dst-degree histogram ----
__global__ __launch_bounds__(256) void k_edge_max(const int* __restrict__ src,
                                                  const int* __restrict__ dst,
                                                  const float* __restrict__ ew,
                                                  const float* __restrict__ as,
                                                  const float* __restrict__ ad,
                                                  unsigned* __restrict__ gmax,
                                                  int* __restrict__ deg) {
  int e = blockIdx.x * 256 + threadIdx.x;
  int s = src[e], d = dst[e];
  float w = ew[e];
  atomicAdd(deg + d, 1);
  float m = -3.4e38f;
#pragma unroll
  for (int hd = 0; hd < HEADS; hd++) {
    float v = as[hd * N_NODES + s] + ad[hd * N_NODES + d];
    v = v >= 0.f ? v : NEG_SLOPE * v;
    v *= w;
    m = fmaxf(m, v);
  }
#pragma unroll
  for (int off = 32; off > 0; off >>= 1) m = fmaxf(m, __shfl_down(m, off));
  __shared__ float red[4];
  int wave = threadIdx.x >> 6, lane = threadIdx.x & 63;
  if (lane == 0) red[wave] = m;
  __syncthreads();
  if (threadIdx.x == 0) {
    float mm = fmaxf(fmaxf(red[0], red[1]), fmaxf(red[2], red[3]));
    atomicMax(gmax, encf(mm));
  }
}

// ---- Scan kernels ----
__global__ __launch_bounds__(256) void k_scan1(const int* __restrict__ deg,
                                               int* __restrict__ excl,
                                               int* __restrict__ bsum) {
  int i = blockIdx.x * 256 + threadIdx.x;
  int orig = (i < N_NODES) ? deg[i] : 0;
  int v = orig;
  int lane = threadIdx.x & 63, wave = threadIdx.x >> 6;
#pragma unroll
  for (int off = 1; off < 64; off <<= 1) {
    int u = __shfl_up(v, off);
    if (lane >= off) v += u;
  }
  __shared__ int wsum[4];
  if (lane == 63) wsum[wave] = v;
  __syncthreads();
  int base = 0;
  for (int w = 0; w < wave; w++) base += wsum[w];
  int incl = v + base;
  if (i < N_NODES) excl[i] = incl - orig;
  if (threadIdx.x == 255) bsum[blockIdx.x] = incl;
}

__global__ __launch_bounds__(256) void k_scan2(int* __restrict__ bsum, int nb) {
  int t = threadIdx.x;
  int orig = (t < nb) ? bsum[t] : 0;
  int v = orig;
  int lane = t & 63, wave = t >> 6;
#pragma unroll
  for (int off = 1; off < 64; off <<= 1) {
    int u = __shfl_up(v, off);
    if (lane >= off) v += u;
  }
  __shared__ int wsum[4];
  if (lane == 63) wsum[wave] = v;
  __syncthreads();
  int base = 0;
  for (int w = 0; w < wave; w++) base += wsum[w];
  if (t < nb) bsum[t] = v + base - orig;
}

__global__ __launch_bounds__(256) void k_scan3(const int* __restrict__ excl,
                                               const int* __restrict__ bsum,
                                               int* __restrict__ row_start,
                                               int* __restrict__ cursor) {
  int i = blockIdx.x * 256 + threadIdx.x;
  if (i < N_NODES) {
    int rs = excl[i] + bsum[blockIdx.x];
    row_start[i] = rs;
    cursor[i] = rs;
  }
}

// ---- Kernel 4: counting-sort scatter of minimal 8B records (src, ew) ----
__global__ __launch_bounds__(256) void k_scatter(const int* __restrict__ src,
                                                 const int* __restrict__ dst,
                                                 const float* __restrict__ ew,
                                                 int* __restrict__ cursor,
                                                 int2* __restrict__ rec) {
  int e = blockIdx.x * 256 + threadIdx.x;
  int s = src[e], d = dst[e];
  float w = ew[e];
  int pos = atomicAdd(cursor + d, 1);
  rec[pos] = make_int2(s, __float_as_int(w));
}

// ---- Kernel 5: wave-autonomous aggregation. One dst node per WAVE, zero
// __syncthreads. 2 edges per step: lanes 0-31 = edge j, lanes 32-63 = edge
// j+1, uint4 (8 bf16 cols) per lane.
__global__ __launch_bounds__(256) void k_agg(const int* __restrict__ row_start,
                                             const int* __restrict__ deg,
                                             const int2* __restrict__ rec,
                                             const float* __restrict__ as,
                                             const float* __restrict__ ad,
                                             const unsigned* __restrict__ gmax,
                                             const unsigned short* __restrict__ hb,
                                             float* __restrict__ out) {
  __shared__ float sal[4][4][68];  // [wave][head][edge-in-chunk], padded stride
  const int t = threadIdx.x;
  const int wv = t >> 6, lane = t & 63;
  const int half = lane >> 5, li = lane & 31;
  const int hd8 = li >> 3;                 // head of this lane's 8 columns
  const int d = blockIdx.x * 4 + wv;       // 12500*4 == 50000 exactly
  const int rs = row_start[d];
  const int dg = deg[d];
  const float gm = decf(*gmax);
  const float ad0 = ad[0 * N_NODES + d];
  const float ad1 = ad[1 * N_NODES + d];
  const float ad2 = ad[2 * N_NODES + d];
  const float ad3 = ad[3 * N_NODES + d];
  float ax = 0.f, ay = 0.f, az = 0.f, aw = 0.f;   // cols li*8+0..3
  float bx = 0.f, by = 0.f, bz = 0.f, bw = 0.f;   // cols li*8+4..7
  float den = 0.f;

  for (int j0 = 0; j0 < dg; j0 += 64) {
    const int nj = min(64, dg - j0);
    int se = 0;
    float we = 0.f;
    if (lane < nj) {
      int2 r = rec[rs + j0 + lane];
      se = r.x;
      we = __int_as_float(r.y);
    }
    {
      float v0 = as[0 * N_NODES + se] + ad0;
      float v1 = as[1 * N_NODES + se] + ad1;
      float v2 = as[2 * N_NODES + se] + ad2;
      float v3 = as[3 * N_NODES + se] + ad3;
      v0 = v0 >= 0.f ? v0 : NEG_SLOPE * v0;
      v1 = v1 >= 0.f ? v1 : NEG_SLOPE * v1;
      v2 = v2 >= 0.f ? v2 : NEG_SLOPE * v2;
      v3 = v3 >= 0.f ? v3 : NEG_SLOPE * v3;
      bool ok = lane < nj;
      sal[wv][0][lane] = ok ? __expf(v0 * we - gm) : 0.f;
      sal[wv][1][lane] = ok ? __expf(v1 * we - gm) : 0.f;
      sal[wv][2][lane] = ok ? __expf(v2 * we - gm) : 0.f;
      sal[wv][3][lane] = ok ? __expf(v3 * we - gm) : 0.f;
    }
    // wave-local fence: ds_writes complete before cross-lane reads
    asm volatile("s_waitcnt lgkmcnt(0)" ::: "memory");
    const float* salh = sal[wv][hd8];

    int j = 0;
    for (; j + 3 < nj; j += 4) {
      int sj0 = __shfl(se, j + half);
      int sj1 = __shfl(se, j + 2 + half);
      float a0 = salh[j + half];
      float a1 = salh[j + 2 + half];
      uint4 q0 = *(const uint4*)(hb + (size_t)sj0 * HF + li * 8);
      uint4 q1 = *(const uint4*)(hb + (size_t)sj1 * HF + li * 8);
      den += a0 + a1;
      ax += a0 * bflo(q0.x) + a1 * bflo(q1.x);
      ay += a0 * bfhi(q0.x) + a1 * bfhi(q1.x);
      az += a0 * bflo(q0.y) + a1 * bflo(q1.y);
      aw += a0 * bfhi(q0.y) + a1 * bfhi(q1.y);
      bx += a0 * bflo(q0.z) + a1 * bflo(q1.z);
      by += a0 * bfhi(q0.z) + a1 * bfhi(q1.z);
      bz += a0 * bflo(q0.w) + a1 * bflo(q1.w);
      bw += a0 * bfhi(q0.w) + a1 * bfhi(q1.w);
    }
    for (; j < nj; j += 2) {
      int sj0 = __shfl(se, min(j + half, nj - 1));
      float a0 = (j + half < nj) ? salh[j + half] : 0.f;
      uint4 q0 = *(const uint4*)(hb + (size_t)sj0 * HF + li * 8);
      den += a0;
      ax += a0 * bflo(q0.x);
      ay += a0 * bfhi(q0.x);
      az += a0 * bflo(q0.y);
      aw += a0 * bfhi(q0.y);
      bx += a0 * bflo(q0.z);
      by += a0 * bfhi(q0.z);
      bz += a0 * bflo(q0.w);
      bw += a0 * bfhi(q0.w);
    }
  }

  ax += __shfl_xor(ax, 32); ay += __shfl_xor(ay, 32);
  az += __shfl_xor(az, 32); aw += __shfl_xor(aw, 32);
  bx += __shfl_xor(bx, 32); by += __shfl_xor(by, 32);
  bz += __shfl_xor(bz, 32); bw += __shfl_xor(bw, 32);
  den += __shfl_xor(den, 32);
  float inv = 1.f / (den + 1e-10f);
  float4 r;
  if (half == 0) r = make_float4(ax * inv, ay * inv, az * inv, aw * inv);
  else           r = make_float4(bx * inv, by * inv, bz * inv, bw * inv);
  *(float4*)(out + (size_t)d * HF + li * 8 + half * 4) = r;
}

extern "C" void kernel_launch(void* const* d_in, const int* in_sizes, int n_in,
                              void* d_out, int out_size, void* d_ws, size_t ws_size,
                              hipStream_t stream) {
  const float* x     = (const float*)d_in[0];
  const int*   ei    = (const int*)d_in[1];
  const float* ew    = (const float*)d_in[2];
  const float* W     = (const float*)d_in[3];
  const float* a_src = (const float*)d_in[4];
  const float* a_dst = (const float*)d_in[5];
  float* out = (float*)d_out;

  // workspace: hb | wb | as | ad | deg | excl | row_start | cursor | rec | bsum | gmax
  unsigned short* hb = (unsigned short*)d_ws;            // 12.8M ushort (25.6 MB)
  unsigned short* wbp = hb + (size_t)N_NODES * HF;       // 65536 ushort
  float* as = (float*)(wbp + 65536);                     // 200K f
  float* ad = as + (size_t)HEADS * N_NODES;              // 200K f
  int* deg       = (int*)(ad + (size_t)HEADS * N_NODES);
  int* excl      = deg + N_NODES;
  int* row_start = excl + N_NODES;
  int* cursor    = row_start + N_NODES;
  int2* rec      = (int2*)(cursor + N_NODES);            // 800K int2
  int* bsum      = (int*)(rec + N_EDGES);
  unsigned* gmax = (unsigned*)(bsum + 256);

  const int* src = ei;
  const int* dst = ei + N_EDGES;
  const int NB = (N_NODES + 255) / 256;  // 196

  hipMemsetAsync(deg, 0, (size_t)N_NODES * sizeof(int), stream);
  hipMemsetAsync(gmax, 0, sizeof(unsigned), stream);

  k_pack_w<<<256, 256, 0, stream>>>(W, wbp);
  k_gemm<<<782, 256, 0, stream>>>(x, wbp, a_src, a_dst, hb, as, ad);
  k_edge_max<<<N_EDGES / 256, 256, 0, stream>>>(src, dst, ew, as, ad, gmax, deg);
  k_scan1<<<NB, 256, 0, stream>>>(deg, excl, bsum);
  k_scan2<<<1, 256, 0, stream>>>(bsum, NB);
  k_scan3<<<NB, 256, 0, stream>>>(excl, bsum, row_start, cursor);
  k_scatter<<<N_EDGES / 256, 256, 0, stream>>>(src, dst, ew, cursor, rec);
  k_agg<<<N_NODES / 4, 256, 0, stream>>>(row_start, deg, rec, as, ad, gmax, hb, out);
}

// Round 4
// 318.827 us; speedup vs baseline: 1.0028x; 1.0028x over previous
//
#include <hip/hip_runtime.h>

#define N_NODES 50000
#define N_EDGES 800000
#define IN_F 256
#define OUT_F 64
#define HEADS 4
#define HF 256  // HEADS*OUT_F
#define NEG_SLOPE 0.2f

typedef __bf16 bf16x8 __attribute__((ext_vector_type(8)));
typedef float f32x4 __attribute__((ext_vector_type(4)));

// ---- monotone float<->uint encoding for atomicMax on floats ----
__device__ __forceinline__ unsigned encf(float f) {
  unsigned u = __float_as_uint(f);
  return (u & 0x80000000u) ? ~u : (u | 0x80000000u);
}
__device__ __forceinline__ float decf(unsigned k) {
  unsigned u = (k & 0x80000000u) ? (k & 0x7FFFFFFFu) : ~k;
  return __uint_as_float(u);
}
// fp32 -> bf16 (round-to-nearest-even)
__device__ __forceinline__ unsigned short f2bf(float f) {
  unsigned u = __float_as_uint(f);
  u += 0x7FFFu + ((u >> 16) & 1u);
  return (unsigned short)(u >> 16);
}
__device__ __forceinline__ float bflo(unsigned u) { return __uint_as_float(u << 16); }
__device__ __forceinline__ float bfhi(unsigned u) { return __uint_as_float(u & 0xFFFF0000u); }

// ---- Pack W into MFMA B-fragment layout (bf16) ----
__global__ __launch_bounds__(256) void k_pack_w(const float* __restrict__ W,
                                                unsigned short* __restrict__ wb) {
  int idx = blockIdx.x * 256 + threadIdx.x;  // 65536
  int j = idx & 7, l = (idx >> 3) & 63, kt = (idx >> 9) & 7;
  int w = (idx >> 12) & 3, hd = (idx >> 14) & 3;
  int k = kt * 32 + (l >> 4) * 8 + j;
  int o = w * 16 + (l & 15);
  wb[idx] = f2bf(W[((size_t)hd * IN_F + k) * OUT_F + o]);
}

// ---- Kernel 1: MFMA GEMM h = x@W (f32 in, bf16 MFMA, fp32 acc) ----
// Block = 64 rows x ALL 256 cols. Wave w owns head w. Attn logits written
// interleaved [node][head] (float4 per node) for gather-friendly access.
__global__ __launch_bounds__(256) void k_gemm(const float* __restrict__ x,
                                              const unsigned short* __restrict__ wb,
                                              const float* __restrict__ a_src,
                                              const float* __restrict__ a_dst,
                                              unsigned short* __restrict__ hb,
                                              float* __restrict__ as_out,
                                              float* __restrict__ ad_out) {
  const int t = threadIdx.x;
  const int hd = t >> 6, l = t & 63;
  const int quad = l >> 4, col = l & 15;
  const int blk = blockIdx.x;
  f32x4 acc[4][4];
#pragma unroll
  for (int ms = 0; ms < 4; ms++)
#pragma unroll
    for (int nt = 0; nt < 4; nt++) acc[ms][nt] = (f32x4){0.f, 0.f, 0.f, 0.f};

  const float* ab[4];
#pragma unroll
  for (int ms = 0; ms < 4; ms++) {
    int mt = blk * 4 + ms;
    if (mt > 3124) mt = 3124;  // tail: compute duplicated, stores guarded by m<N
    ab[ms] = x + (size_t)(mt * 16 + col) * IN_F + quad * 8;
  }
  const unsigned short* wbase = wb + (size_t)hd * 16384 + l * 8;

  for (int kt = 0; kt < 8; kt++) {
    union { uint4 u; bf16x8 v; } b[4], a[4];
#pragma unroll
    for (int nt = 0; nt < 4; nt++)
      b[nt].u = *(const uint4*)(wbase + (nt * 8 + kt) * 512);
#pragma unroll
    for (int ms = 0; ms < 4; ms++) {
      float4 v0 = *(const float4*)(ab[ms] + kt * 32);
      float4 v1 = *(const float4*)(ab[ms] + kt * 32 + 4);
      uint4 o;
      o.x = (unsigned)f2bf(v0.x) | ((unsigned)f2bf(v0.y) << 16);
      o.y = (unsigned)f2bf(v0.z) | ((unsigned)f2bf(v0.w) << 16);
      o.z = (unsigned)f2bf(v1.x) | ((unsigned)f2bf(v1.y) << 16);
      o.w = (unsigned)f2bf(v1.z) | ((unsigned)f2bf(v1.w) << 16);
      a[ms].u = o;
    }
#pragma unroll
    for (int ms = 0; ms < 4; ms++)
#pragma unroll
      for (int nt = 0; nt < 4; nt++)
        acc[ms][nt] = __builtin_amdgcn_mfma_f32_16x16x32_bf16(a[ms].v, b[nt].v, acc[ms][nt], 0, 0, 0);
  }

  // C/D layout: col = lane&15, row = quad*4 + r  [verified m89/m91]
  float avs[4], avd[4];
#pragma unroll
  for (int nt = 0; nt < 4; nt++) {
    avs[nt] = a_src[hd * OUT_F + nt * 16 + col];
    avd[nt] = a_dst[hd * OUT_F + nt * 16 + col];
  }
#pragma unroll
  for (int ms = 0; ms < 4; ms++) {
    int mbase = blk * 64 + ms * 16 + quad * 4;
#pragma unroll
    for (int r = 0; r < 4; r++) {
      int m = mbase + r;
      float ps = 0.f, pd = 0.f;
#pragma unroll
      for (int nt = 0; nt < 4; nt++) {
        float hv = acc[ms][nt][r];
        if (m < N_NODES)
          hb[(size_t)m * HF + hd * OUT_F + nt * 16 + col] = f2bf(hv);
        ps += hv * avs[nt];
        pd += hv * avd[nt];
      }
#pragma unroll
      for (int off = 8; off > 0; off >>= 1) {
        ps += __shfl_down(ps, off, 16);
        pd += __shfl_down(pd, off, 16);
      }
      if (col == 0 && m < N_NODES) {
        as_out[m * 4 + hd] = ps;   // [node][head] interleaved
        ad_out[m * 4 + hd] = pd;
      }
    }
  }
}

// ---- Kernel 2: global max of e over [H,E] + dst-degree histogram ----
// as/ad are [node][4] -> one 16B gather per endpoint (vs 8x4B scattered).
__global__ __launch_bounds__(256) void k_edge_max(const int* __restrict__ src,
                                                  const int* __restrict__ dst,
                                                  const float* __restrict__ ew,
                                                  const float* __restrict__ as,
                                                  const float* __restrict__ ad,
                                                  unsigned* __restrict__ gmax,
                                                  int* __restrict__ deg) {
  int e = blockIdx.x * 256 + threadIdx.x;
  int s = src[e], d = dst[e];
  float w = ew[e];
  atomicAdd(deg + d, 1);
  float4 a = *(const float4*)(as + (size_t)s * 4);
  float4 b = *(const float4*)(ad + (size_t)d * 4);
  float v0 = a.x + b.x, v1 = a.y + b.y, v2 = a.z + b.z, v3 = a.w + b.w;
  v0 = v0 >= 0.f ? v0 : NEG_SLOPE * v0;
  v1 = v1 >= 0.f ? v1 : NEG_SLOPE * v1;
  v2 = v2 >= 0.f ? v2 : NEG_SLOPE * v2;
  v3 = v3 >= 0.f ? v3 : NEG_SLOPE * v3;
  float m = fmaxf(fmaxf(v0, v1), fmaxf(v2, v3)) * w;  // w >= 0 here? no: keep exact
  // exact: multiply each then max (ew may be any sign in general; uniform[0,1) here,
  // but stay faithful)
  m = fmaxf(fmaxf(v0 * w, v1 * w), fmaxf(v2 * w, v3 * w));
#pragma unroll
  for (int off = 32; off > 0; off >>= 1) m = fmaxf(m, __shfl_down(m, off));
  __shared__ float red[4];
  int wave = threadIdx.x >> 6, lane = threadIdx.x & 63;
  if (lane == 0) red[wave] = m;
  __syncthreads();
  if (threadIdx.x == 0) {
    float mm = fmaxf(fmaxf(red[0], red[1]), fmaxf(red[2], red[3]));
    atomicMax(gmax, encf(mm));
  }
}

// ---- Scan kernels ----
__global__ __launch_bounds__(256) void k_scan1(const int* __restrict__ deg,
                                               int* __restrict__ excl,
                                               int* __restrict__ bsum) {
  int i = blockIdx.x * 256 + threadIdx.x;
  int orig = (i < N_NODES) ? deg[i] : 0;
  int v = orig;
  int lane = threadIdx.x & 63, wave = threadIdx.x >> 6;
#pragma unroll
  for (int off = 1; off < 64; off <<= 1) {
    int u = __shfl_up(v, off);
    if (lane >= off) v += u;
  }
  __shared__ int wsum[4];
  if (lane == 63) wsum[wave] = v;
  __syncthreads();
  int base = 0;
  for (int w = 0; w < wave; w++) base += wsum[w];
  int incl = v + base;
  if (i < N_NODES) excl[i] = incl - orig;
  if (threadIdx.x == 255) bsum[blockIdx.x] = incl;
}

__global__ __launch_bounds__(256) void k_scan2(int* __restrict__ bsum, int nb) {
  int t = threadIdx.x;
  int orig = (t < nb) ? bsum[t] : 0;
  int v = orig;
  int lane = t & 63, wave = t >> 6;
#pragma unroll
  for (int off = 1; off < 64; off <<= 1) {
    int u = __shfl_up(v, off);
    if (lane >= off) v += u;
  }
  __shared__ int wsum[4];
  if (lane == 63) wsum[wave] = v;
  __syncthreads();
  int base = 0;
  for (int w = 0; w < wave; w++) base += wsum[w];
  if (t < nb) bsum[t] = v + base - orig;
}

__global__ __launch_bounds__(256) void k_scan3(const int* __restrict__ excl,
                                               const int* __restrict__ bsum,
                                               int* __restrict__ row_start,
                                               int* __restrict__ cursor) {
  int i = blockIdx.x * 256 + threadIdx.x;
  if (i < N_NODES) {
    int rs = excl[i] + bsum[blockIdx.x];
    row_start[i] = rs;
    cursor[i] = rs;
  }
}

// ---- Kernel 4: counting-sort scatter of minimal 8B records (src, ew) ----
__global__ __launch_bounds__(256) void k_scatter(const int* __restrict__ src,
                                                 const int* __restrict__ dst,
                                                 const float* __restrict__ ew,
                                                 int* __restrict__ cursor,
                                                 int2* __restrict__ rec) {
  int e = blockIdx.x * 256 + threadIdx.x;
  int s = src[e], d = dst[e];
  float w = ew[e];
  int pos = atomicAdd(cursor + d, 1);
  rec[pos] = make_int2(s, __float_as_int(w));
}

// ---- Kernel 5: wave-autonomous aggregation. One dst node per WAVE, zero
// __syncthreads. 8 edges per main-loop step: lanes 0-31 = even edge,
// lanes 32-63 = odd edge, 4 independent uint4 gathers in flight per lane.
__global__ __launch_bounds__(256) void k_agg(const int* __restrict__ row_start,
                                             const int* __restrict__ deg,
                                             const int2* __restrict__ rec,
                                             const float* __restrict__ as,
                                             const float* __restrict__ ad,
                                             const unsigned* __restrict__ gmax,
                                             const unsigned short* __restrict__ hb,
                                             float* __restrict__ out) {
  __shared__ float sal[4][4][68];  // [wave][head][edge-in-chunk], padded stride
  const int t = threadIdx.x;
  const int wv = t >> 6, lane = t & 63;
  const int half = lane >> 5, li = lane & 31;
  const int hd8 = li >> 3;                 // head of this lane's 8 columns
  const int d = blockIdx.x * 4 + wv;       // 12500*4 == 50000 exactly
  const int rs = row_start[d];
  const int dg = deg[d];
  const float gm = decf(*gmax);
  const float4 adv = *(const float4*)(ad + (size_t)d * 4);
  float ax = 0.f, ay = 0.f, az = 0.f, aw = 0.f;   // cols li*8+0..3
  float bx = 0.f, by = 0.f, bz = 0.f, bw = 0.f;   // cols li*8+4..7
  float den = 0.f;

  for (int j0 = 0; j0 < dg; j0 += 64) {
    const int nj = min(64, dg - j0);
    int se = 0;
    float we = 0.f;
    if (lane < nj) {
      int2 r = rec[rs + j0 + lane];
      se = r.x;
      we = __int_as_float(r.y);
    }
    {
      float4 a4 = *(const float4*)(as + (size_t)se * 4);  // one 16B gather
      float v0 = a4.x + adv.x;
      float v1 = a4.y + adv.y;
      float v2 = a4.z + adv.z;
      float v3 = a4.w + adv.w;
      v0 = v0 >= 0.f ? v0 : NEG_SLOPE * v0;
      v1 = v1 >= 0.f ? v1 : NEG_SLOPE * v1;
      v2 = v2 >= 0.f ? v2 : NEG_SLOPE * v2;
      v3 = v3 >= 0.f ? v3 : NEG_SLOPE * v3;
      bool ok = lane < nj;
      sal[wv][0][lane] = ok ? __expf(v0 * we - gm) : 0.f;
      sal[wv][1][lane] = ok ? __expf(v1 * we - gm) : 0.f;
      sal[wv][2][lane] = ok ? __expf(v2 * we - gm) : 0.f;
      sal[wv][3][lane] = ok ? __expf(v3 * we - gm) : 0.f;
    }
    // wave-local fence: ds_writes complete before cross-lane reads
    asm volatile("s_waitcnt lgkmcnt(0)" ::: "memory");
    const float* salh = sal[wv][hd8];

    int j = 0;
    for (; j + 7 < nj; j += 8) {
      int sj0 = __shfl(se, j + half);
      int sj1 = __shfl(se, j + 2 + half);
      int sj2 = __shfl(se, j + 4 + half);
      int sj3 = __shfl(se, j + 6 + half);
      uint4 q0 = *(const uint4*)(hb + (size_t)sj0 * HF + li * 8);
      uint4 q1 = *(const uint4*)(hb + (size_t)sj1 * HF + li * 8);
      uint4 q2 = *(const uint4*)(hb + (size_t)sj2 * HF + li * 8);
      uint4 q3 = *(const uint4*)(hb + (size_t)sj3 * HF + li * 8);
      float a0 = salh[j + half];
      float a1 = salh[j + 2 + half];
      float a2 = salh[j + 4 + half];
      float a3 = salh[j + 6 + half];
      den += (a0 + a1) + (a2 + a3);
      ax += a0 * bflo(q0.x) + a1 * bflo(q1.x) + a2 * bflo(q2.x) + a3 * bflo(q3.x);
      ay += a0 * bfhi(q0.x) + a1 * bfhi(q1.x) + a2 * bfhi(q2.x) + a3 * bfhi(q3.x);
      az += a0 * bflo(q0.y) + a1 * bflo(q1.y) + a2 * bflo(q2.y) + a3 * bflo(q3.y);
      aw += a0 * bfhi(q0.y) + a1 * bfhi(q1.y) + a2 * bfhi(q2.y) + a3 * bfhi(q3.y);
      bx += a0 * bflo(q0.z) + a1 * bflo(q1.z) + a2 * bflo(q2.z) + a3 * bflo(q3.z);
      by += a0 * bfhi(q0.z) + a1 * bfhi(q1.z) + a2 * bfhi(q2.z) + a3 * bfhi(q3.z);
      bz += a0 * bflo(q0.w) + a1 * bflo(q1.w) + a2 * bflo(q2.w) + a3 * bflo(q3.w);
      bw += a0 * bfhi(q0.w) + a1 * bfhi(q1.w) + a2 * bfhi(q2.w) + a3 * bfhi(q3.w);
    }
    for (; j < nj; j += 2) {
      int sj0 = __shfl(se, min(j + half, nj - 1));
      float a0 = (j + half < nj) ? salh[j + half] : 0.f;
      uint4 q0 = *(const uint4*)(hb + (size_t)sj0 * HF + li * 8);
      den += a0;
      ax += a0 * bflo(q0.x);
      ay += a0 * bfhi(q0.x);
      az += a0 * bflo(q0.y);
      aw += a0 * bfhi(q0.y);
      bx += a0 * bflo(q0.z);
      by += a0 * bfhi(q0.z);
      bz += a0 * bflo(q0.w);
      bw += a0 * bfhi(q0.w);
    }
  }

  // combine the two edge-halves (lane l <-> l^32 hold same columns)
  ax += __shfl_xor(ax, 32); ay += __shfl_xor(ay, 32);
  az += __shfl_xor(az, 32); aw += __shfl_xor(aw, 32);
  bx += __shfl_xor(bx, 32); by += __shfl_xor(by, 32);
  bz += __shfl_xor(bz, 32); bw += __shfl_xor(bw, 32);
  den += __shfl_xor(den, 32);
  float inv = 1.f / (den + 1e-10f);
  float4 r;
  if (half == 0) r = make_float4(ax * inv, ay * inv, az * inv, aw * inv);
  else           r = make_float4(bx * inv, by * inv, bz * inv, bw * inv);
  *(float4*)(out + (size_t)d * HF + li * 8 + half * 4) = r;
}

extern "C" void kernel_launch(void* const* d_in, const int* in_sizes, int n_in,
                              void* d_out, int out_size, void* d_ws, size_t ws_size,
                              hipStream_t stream) {
  const float* x     = (const float*)d_in[0];
  const int*   ei    = (const int*)d_in[1];
  const float* ew    = (const float*)d_in[2];
  const float* W     = (const float*)d_in[3];
  const float* a_src = (const float*)d_in[4];
  const float* a_dst = (const float*)d_in[5];
  float* out = (float*)d_out;

  // workspace: hb | wb | as | ad | deg | excl | row_start | cursor | rec | bsum | gmax
  unsigned short* hb = (unsigned short*)d_ws;            // 12.8M ushort (25.6 MB)
  unsigned short* wbp = hb + (size_t)N_NODES * HF;       // 65536 ushort
  float* as = (float*)(wbp + 65536);                     // 200K f, [node][4]
  float* ad = as + (size_t)HEADS * N_NODES;              // 200K f, [node][4]
  int* deg       = (int*)(ad + (size_t)HEADS * N_NODES);
  int* excl      = deg + N_NODES;
  int* row_start = excl + N_NODES;
  int* cursor    = row_start + N_NODES;
  int2* rec      = (int2*)(cursor + N_NODES);            // 800K int2
  int* bsum      = (int*)(rec + N_EDGES);
  unsigned* gmax = (unsigned*)(bsum + 256);

  const int* src = ei;
  const int* dst = ei + N_EDGES;
  const int NB = (N_NODES + 255) / 256;  // 196

  hipMemsetAsync(deg, 0, (size_t)N_NODES * sizeof(int), stream);
  hipMemsetAsync(gmax, 0, sizeof(unsigned), stream);

  k_pack_w<<<256, 256, 0, stream>>>(W, wbp);
  k_gemm<<<782, 256, 0, stream>>>(x, wbp, a_src, a_dst, hb, as, ad);
  k_edge_max<<<N_EDGES / 256, 256, 0, stream>>>(src, dst, ew, as, ad, gmax, deg);
  k_scan1<<<NB, 256, 0, stream>>>(deg, excl, bsum);
  k_scan2<<<1, 256, 0, stream>>>(bsum, NB);
  k_scan3<<<NB, 256, 0, stream>>>(excl, bsum, row_start, cursor);
  k_scatter<<<N_EDGES / 256, 256, 0, stream>>>(src, dst, ew, cursor, rec);
  k_agg<<<N_NODES / 4, 256, 0, stream>>>(row_start, deg, rec, as, ad, gmax, hb, out);
}

// Round 5
// 310.917 us; speedup vs baseline: 1.0283x; 1.0254x over previous
//
#include <hip/hip_runtime.h>

#define N_NODES 50000
#define N_EDGES 800000
#define IN_F 256
#define OUT_F 64
#define HEADS 4
#define HF 256  // HEADS*OUT_F
#define NEG_SLOPE 0.2f

typedef __bf16 bf16x8 __attribute__((ext_vector_type(8)));
typedef float f32x4 __attribute__((ext_vector_type(4)));

// ---- monotone float<->uint encoding for atomicMax on floats ----
__device__ __forceinline__ unsigned encf(float f) {
  unsigned u = __float_as_uint(f);
  return (u & 0x80000000u) ? ~u : (u | 0x80000000u);
}
__device__ __forceinline__ float decf(unsigned k) {
  unsigned u = (k & 0x80000000u) ? (k & 0x7FFFFFFFu) : ~k;
  return __uint_as_float(u);
}
// fp32 -> bf16 (round-to-nearest-even)
__device__ __forceinline__ unsigned short f2bf(float f) {
  unsigned u = __float_as_uint(f);
  u += 0x7FFFu + ((u >> 16) & 1u);
  return (unsigned short)(u >> 16);
}
__device__ __forceinline__ float bflo(unsigned u) { return __uint_as_float(u << 16); }
__device__ __forceinline__ float bfhi(unsigned u) { return __uint_as_float(u & 0xFFFF0000u); }

// ---- Pack W into MFMA B-fragment layout (bf16); also zero deg/gmax
// (fused memsets: 65536 threads >= N_NODES; runs before edge_max in-stream).
__global__ __launch_bounds__(256) void k_pack_w(const float* __restrict__ W,
                                                unsigned short* __restrict__ wb,
                                                int* __restrict__ deg,
                                                unsigned* __restrict__ gmax) {
  int idx = blockIdx.x * 256 + threadIdx.x;  // 65536
  if (idx < N_NODES) deg[idx] = 0;
  if (idx == 0) *gmax = 0u;
  int j = idx & 7, l = (idx >> 3) & 63, kt = (idx >> 9) & 7;
  int w = (idx >> 12) & 3, hd = (idx >> 14) & 3;
  int k = kt * 32 + (l >> 4) * 8 + j;
  int o = w * 16 + (l & 15);
  wb[idx] = f2bf(W[((size_t)hd * IN_F + k) * OUT_F + o]);
}

// ---- Pack x: row-major f32 -> bf16 cast, fully coalesced (no interleave).
// Conversion done ONCE here instead of 4x redundantly per gemm block.
__global__ __launch_bounds__(256) void k_pack_x(const float* __restrict__ x,
                                                unsigned short* __restrict__ xb) {
  int tid = blockIdx.x * 256 + threadIdx.x;  // 1.6M = 50000*256/8
  const float* px = x + (size_t)tid * 8;
  float4 v0 = *(const float4*)px;
  float4 v1 = *(const float4*)(px + 4);
  uint4 o;
  o.x = (unsigned)f2bf(v0.x) | ((unsigned)f2bf(v0.y) << 16);
  o.y = (unsigned)f2bf(v0.z) | ((unsigned)f2bf(v0.w) << 16);
  o.z = (unsigned)f2bf(v1.x) | ((unsigned)f2bf(v1.y) << 16);
  o.w = (unsigned)f2bf(v1.z) | ((unsigned)f2bf(v1.w) << 16);
  *(uint4*)(xb + (size_t)tid * 8) = o;
}

// ---- Kernel 1: MFMA GEMM h = xb@W (bf16 in, fp32 acc) ----
// Block = 64 rows x ALL 256 cols. Wave w owns head w (4 Mtiles x 4 Ntiles,
// 128 MFMAs). A-frags load straight from row-major bf16 xb: one 16B load
// per (ms,kt); a wave's 64 lanes cover 16 rows x 64B = 16 full lines.
// Inner loop is loads+MFMA only (no conversion VALU).
__global__ __launch_bounds__(256) void k_gemm(const unsigned short* __restrict__ xb,
                                              const unsigned short* __restrict__ wb,
                                              const float* __restrict__ a_src,
                                              const float* __restrict__ a_dst,
                                              unsigned short* __restrict__ hb,
                                              float* __restrict__ as_out,
                                              float* __restrict__ ad_out) {
  const int t = threadIdx.x;
  const int hd = t >> 6, l = t & 63;
  const int quad = l >> 4, col = l & 15;
  const int blk = blockIdx.x;
  f32x4 acc[4][4];
#pragma unroll
  for (int ms = 0; ms < 4; ms++)
#pragma unroll
    for (int nt = 0; nt < 4; nt++) acc[ms][nt] = (f32x4){0.f, 0.f, 0.f, 0.f};

  const unsigned short* ab[4];
#pragma unroll
  for (int ms = 0; ms < 4; ms++) {
    int mt = blk * 4 + ms;
    if (mt > 3124) mt = 3124;  // tail: compute duplicated, stores guarded by m<N
    ab[ms] = xb + (size_t)(mt * 16 + col) * IN_F + quad * 8;
  }
  const unsigned short* wbase = wb + (size_t)hd * 16384 + l * 8;

  for (int kt = 0; kt < 8; kt++) {
    union { uint4 u; bf16x8 v; } b[4], a[4];
#pragma unroll
    for (int nt = 0; nt < 4; nt++)
      b[nt].u = *(const uint4*)(wbase + (nt * 8 + kt) * 512);
#pragma unroll
    for (int ms = 0; ms < 4; ms++)
      a[ms].u = *(const uint4*)(ab[ms] + kt * 32);
#pragma unroll
    for (int ms = 0; ms < 4; ms++)
#pragma unroll
      for (int nt = 0; nt < 4; nt++)
        acc[ms][nt] = __builtin_amdgcn_mfma_f32_16x16x32_bf16(a[ms].v, b[nt].v, acc[ms][nt], 0, 0, 0);
  }

  // C/D layout: col = lane&15, row = quad*4 + r  [verified m89/m91]
  float avs[4], avd[4];
#pragma unroll
  for (int nt = 0; nt < 4; nt++) {
    avs[nt] = a_src[hd * OUT_F + nt * 16 + col];
    avd[nt] = a_dst[hd * OUT_F + nt * 16 + col];
  }
#pragma unroll
  for (int ms = 0; ms < 4; ms++) {
    int mbase = blk * 64 + ms * 16 + quad * 4;
#pragma unroll
    for (int r = 0; r < 4; r++) {
      int m = mbase + r;
      float ps = 0.f, pd = 0.f;
#pragma unroll
      for (int nt = 0; nt < 4; nt++) {
        float hv = acc[ms][nt][r];
        if (m < N_NODES)
          hb[(size_t)m * HF + hd * OUT_F + nt * 16 + col] = f2bf(hv);
        ps += hv * avs[nt];
        pd += hv * avd[nt];
      }
#pragma unroll
      for (int off = 8; off > 0; off >>= 1) {
        ps += __shfl_down(ps, off, 16);
        pd += __shfl_down(pd, off, 16);
      }
      if (col == 0 && m < N_NODES) {
        as_out[m * 4 + hd] = ps;   // [node][head] interleaved
        ad_out[m * 4 + hd] = pd;
      }
    }
  }
}

// ---- Kernel 2: global max of e over [H,E] + dst-degree histogram ----
// as/ad are [node][4] -> one 16B gather per endpoint.
__global__ __launch_bounds__(256) void k_edge_max(const int* __restrict__ src,
                                                  const int* __restrict__ dst,
                                                  const float* __restrict__ ew,
                                                  const float* __restrict__ as,
                                                  const float* __restrict__ ad,
                                                  unsigned* __restrict__ gmax,
                                                  int* __restrict__ deg) {
  int e = blockIdx.x * 256 + threadIdx.x;
  int s = src[e], d = dst[e];
  float w = ew[e];
  atomicAdd(deg + d, 1);
  float4 a = *(const float4*)(as + (size_t)s * 4);
  float4 b = *(const float4*)(ad + (size_t)d * 4);
  float v0 = a.x + b.x, v1 = a.y + b.y, v2 = a.z + b.z, v3 = a.w + b.w;
  v0 = v0 >= 0.f ? v0 : NEG_SLOPE * v0;
  v1 = v1 >= 0.f ? v1 : NEG_SLOPE * v1;
  v2 = v2 >= 0.f ? v2 : NEG_SLOPE * v2;
  v3 = v3 >= 0.f ? v3 : NEG_SLOPE * v3;
  float m = fmaxf(fmaxf(v0 * w, v1 * w), fmaxf(v2 * w, v3 * w));
#pragma unroll
  for (int off = 32; off > 0; off >>= 1) m = fmaxf(m, __shfl_down(m, off));
  __shared__ float red[4];
  int wave = threadIdx.x >> 6, lane = threadIdx.x & 63;
  if (lane == 0) red[wave] = m;
  __syncthreads();
  if (threadIdx.x == 0) {
    float mm = fmaxf(fmaxf(red[0], red[1]), fmaxf(red[2], red[3]));
    atomicMax(gmax, encf(mm));
  }
}

// ---- Scan kernels ----
__global__ __launch_bounds__(256) void k_scan1(const int* __restrict__ deg,
                                               int* __restrict__ excl,
                                               int* __restrict__ bsum) {
  int i = blockIdx.x * 256 + threadIdx.x;
  int orig = (i < N_NODES) ? deg[i] : 0;
  int v = orig;
  int lane = threadIdx.x & 63, wave = threadIdx.x >> 6;
#pragma unroll
  for (int off = 1; off < 64; off <<= 1) {
    int u = __shfl_up(v, off);
    if (lane >= off) v += u;
  }
  __shared__ int wsum[4];
  if (lane == 63) wsum[wave] = v;
  __syncthreads();
  int base = 0;
  for (int w = 0; w < wave; w++) base += wsum[w];
  int incl = v + base;
  if (i < N_NODES) excl[i] = incl - orig;
  if (threadIdx.x == 255) bsum[blockIdx.x] = incl;
}

__global__ __launch_bounds__(256) void k_scan2(int* __restrict__ bsum, int nb) {
  int t = threadIdx.x;
  int orig = (t < nb) ? bsum[t] : 0;
  int v = orig;
  int lane = t & 63, wave = t >> 6;
#pragma unroll
  for (int off = 1; off < 64; off <<= 1) {
    int u = __shfl_up(v, off);
    if (lane >= off) v += u;
  }
  __shared__ int wsum[4];
  if (lane == 63) wsum[wave] = v;
  __syncthreads();
  int base = 0;
  for (int w = 0; w < wave; w++) base += wsum[w];
  if (t < nb) bsum[t] = v + base - orig;
}

__global__ __launch_bounds__(256) void k_scan3(const int* __restrict__ excl,
                                               const int* __restrict__ bsum,
                                               int* __restrict__ row_start,
                                               int* __restrict__ cursor) {
  int i = blockIdx.x * 256 + threadIdx.x;
  if (i < N_NODES) {
    int rs = excl[i] + bsum[blockIdx.x];
    row_start[i] = rs;
    cursor[i] = rs;
  }
}

// ---- Kernel 4: counting-sort scatter of minimal 8B records (src, ew) ----
__global__ __launch_bounds__(256) void k_scatter(const int* __restrict__ src,
                                                 const int* __restrict__ dst,
                                                 const float* __restrict__ ew,
                                                 int* __restrict__ cursor,
                                                 int2* __restrict__ rec) {
  int e = blockIdx.x * 256 + threadIdx.x;
  int s = src[e], d = dst[e];
  float w = ew[e];
  int pos = atomicAdd(cursor + d, 1);
  rec[pos] = make_int2(s, __float_as_int(w));
}

// ---- Kernel 5: wave-autonomous aggregation. One dst node per WAVE, zero
// __syncthreads. 8 edges per main-loop step, 4 uint4 gathers in flight/lane.
__global__ __launch_bounds__(256) void k_agg(const int* __restrict__ row_start,
                                             const int* __restrict__ deg,
                                             const int2* __restrict__ rec,
                                             const float* __restrict__ as,
                                             const float* __restrict__ ad,
                                             const unsigned* __restrict__ gmax,
                                             const unsigned short* __restrict__ hb,
                                             float* __restrict__ out) {
  __shared__ float sal[4][4][68];  // [wave][head][edge-in-chunk], padded stride
  const int t = threadIdx.x;
  const int wv = t >> 6, lane = t & 63;
  const int half = lane >> 5, li = lane & 31;
  const int hd8 = li >> 3;                 // head of this lane's 8 columns
  const int d = blockIdx.x * 4 + wv;       // 12500*4 == 50000 exactly
  const int rs = row_start[d];
  const int dg = deg[d];
  const float gm = decf(*gmax);
  const float4 adv = *(const float4*)(ad + (size_t)d * 4);
  float ax = 0.f, ay = 0.f, az = 0.f, aw = 0.f;   // cols li*8+0..3
  float bx = 0.f, by = 0.f, bz = 0.f, bw = 0.f;   // cols li*8+4..7
  float den = 0.f;

  for (int j0 = 0; j0 < dg; j0 += 64) {
    const int nj = min(64, dg - j0);
    int se = 0;
    float we = 0.f;
    if (lane < nj) {
      int2 r = rec[rs + j0 + lane];
      se = r.x;
      we = __int_as_float(r.y);
    }
    {
      float4 a4 = *(const float4*)(as + (size_t)se * 4);  // one 16B gather
      float v0 = a4.x + adv.x;
      float v1 = a4.y + adv.y;
      float v2 = a4.z + adv.z;
      float v3 = a4.w + adv.w;
      v0 = v0 >= 0.f ? v0 : NEG_SLOPE * v0;
      v1 = v1 >= 0.f ? v1 : NEG_SLOPE * v1;
      v2 = v2 >= 0.f ? v2 : NEG_SLOPE * v2;
      v3 = v3 >= 0.f ? v3 : NEG_SLOPE * v3;
      bool ok = lane < nj;
      sal[wv][0][lane] = ok ? __expf(v0 * we - gm) : 0.f;
      sal[wv][1][lane] = ok ? __expf(v1 * we - gm) : 0.f;
      sal[wv][2][lane] = ok ? __expf(v2 * we - gm) : 0.f;
      sal[wv][3][lane] = ok ? __expf(v3 * we - gm) : 0.f;
    }
    // wave-local fence: ds_writes complete before cross-lane reads
    asm volatile("s_waitcnt lgkmcnt(0)" ::: "memory");
    const float* salh = sal[wv][hd8];

    int j = 0;
    for (; j + 7 < nj; j += 8) {
      int sj0 = __shfl(se, j + half);
      int sj1 = __shfl(se, j + 2 + half);
      int sj2 = __shfl(se, j + 4 + half);
      int sj3 = __shfl(se, j + 6 + half);
      uint4 q0 = *(const uint4*)(hb + (size_t)sj0 * HF + li * 8);
      uint4 q1 = *(const uint4*)(hb + (size_t)sj1 * HF + li * 8);
      uint4 q2 = *(const uint4*)(hb + (size_t)sj2 * HF + li * 8);
      uint4 q3 = *(const uint4*)(hb + (size_t)sj3 * HF + li * 8);
      float a0 = salh[j + half];
      float a1 = salh[j + 2 + half];
      float a2 = salh[j + 4 + half];
      float a3 = salh[j + 6 + half];
      den += (a0 + a1) + (a2 + a3);
      ax += a0 * bflo(q0.x) + a1 * bflo(q1.x) + a2 * bflo(q2.x) + a3 * bflo(q3.x);
      ay += a0 * bfhi(q0.x) + a1 * bfhi(q1.x) + a2 * bfhi(q2.x) + a3 * bfhi(q3.x);
      az += a0 * bflo(q0.y) + a1 * bflo(q1.y) + a2 * bflo(q2.y) + a3 * bflo(q3.y);
      aw += a0 * bfhi(q0.y) + a1 * bfhi(q1.y) + a2 * bfhi(q2.y) + a3 * bfhi(q3.y);
      bx += a0 * bflo(q0.z) + a1 * bflo(q1.z) + a2 * bflo(q2.z) + a3 * bflo(q3.z);
      by += a0 * bfhi(q0.z) + a1 * bfhi(q1.z) + a2 * bfhi(q2.z) + a3 * bfhi(q3.z);
      bz += a0 * bflo(q0.w) + a1 * bflo(q1.w) + a2 * bflo(q2.w) + a3 * bflo(q3.w);
      bw += a0 * bfhi(q0.w) + a1 * bfhi(q1.w) + a2 * bfhi(q2.w) + a3 * bfhi(q3.w);
    }
    for (; j < nj; j += 2) {
      int sj0 = __shfl(se, min(j + half, nj - 1));
      float a0 = (j + half < nj) ? salh[j + half] : 0.f;
      uint4 q0 = *(const uint4*)(hb + (size_t)sj0 * HF + li * 8);
      den += a0;
      ax += a0 * bflo(q0.x);
      ay += a0 * bfhi(q0.x);
      az += a0 * bflo(q0.y);
      aw += a0 * bfhi(q0.y);
      bx += a0 * bflo(q0.z);
      by += a0 * bfhi(q0.z);
      bz += a0 * bflo(q0.w);
      bw += a0 * bfhi(q0.w);
    }
  }

  // combine the two edge-halves (lane l <-> l^32 hold same columns)
  ax += __shfl_xor(ax, 32); ay += __shfl_xor(ay, 32);
  az += __shfl_xor(az, 32); aw += __shfl_xor(aw, 32);
  bx += __shfl_xor(bx, 32); by += __shfl_xor(by, 32);
  bz += __shfl_xor(bz, 32); bw += __shfl_xor(bw, 32);
  den += __shfl_xor(den, 32);
  float inv = 1.f / (den + 1e-10f);
  float4 r;
  if (half == 0) r = make_float4(ax * inv, ay * inv, az * inv, aw * inv);
  else           r = make_float4(bx * inv, by * inv, bz * inv, bw * inv);
  *(float4*)(out + (size_t)d * HF + li * 8 + half * 4) = r;
}

extern "C" void kernel_launch(void* const* d_in, const int* in_sizes, int n_in,
                              void* d_out, int out_size, void* d_ws, size_t ws_size,
                              hipStream_t stream) {
  const float* x     = (const float*)d_in[0];
  const int*   ei    = (const int*)d_in[1];
  const float* ew    = (const float*)d_in[2];
  const float* W     = (const float*)d_in[3];
  const float* a_src = (const float*)d_in[4];
  const float* a_dst = (const float*)d_in[5];
  float* out = (float*)d_out;

  // workspace: hb | xb | wb | as | ad | deg | excl | row_start | cursor | rec | bsum | gmax
  unsigned short* hb = (unsigned short*)d_ws;            // 12.8M ushort (25.6 MB)
  unsigned short* xb = hb + (size_t)N_NODES * HF;        // 12.8M ushort (25.6 MB)
  unsigned short* wbp = xb + (size_t)N_NODES * IN_F;     // 65536 ushort
  float* as = (float*)(wbp + 65536);                     // 200K f, [node][4]
  float* ad = as + (size_t)HEADS * N_NODES;              // 200K f, [node][4]
  int* deg       = (int*)(ad + (size_t)HEADS * N_NODES);
  int* excl      = deg + N_NODES;
  int* row_start = excl + N_NODES;
  int* cursor    = row_start + N_NODES;
  int2* rec      = (int2*)(cursor + N_NODES);            // 800K int2
  int* bsum      = (int*)(rec + N_EDGES);
  unsigned* gmax = (unsigned*)(bsum + 256);

  const int* src = ei;
  const int* dst = ei + N_EDGES;
  const int NB = (N_NODES + 255) / 256;  // 196

  k_pack_w<<<256, 256, 0, stream>>>(W, wbp, deg, gmax);  // also zeroes deg/gmax
  k_pack_x<<<6250, 256, 0, stream>>>(x, xb);
  k_gemm<<<782, 256, 0, stream>>>(xb, wbp, a_src, a_dst, hb, as, ad);
  k_edge_max<<<N_EDGES / 256, 256, 0, stream>>>(src, dst, ew, as, ad, gmax, deg);
  k_scan1<<<NB, 256, 0, stream>>>(deg, excl, bsum);
  k_scan2<<<1, 256, 0, stream>>>(bsum, NB);
  k_scan3<<<NB, 256, 0, stream>>>(excl, bsum, row_start, cursor);
  k_scatter<<<N_EDGES / 256, 256, 0, stream>>>(src, dst, ew, cursor, rec);
  k_agg<<<N_NODES / 4, 256, 0, stream>>>(row_start, deg, rec, as, ad, gmax, hb, out);
}